// Round 1
// baseline (8752.944 us; speedup 1.0000x reference)
//
#include <hip/hip_runtime.h>
#include <cstddef>
#include <cstdint>

// Problem constants (GOFA decoder layer)
constexpr int kN    = 1024;
constexpr int kE    = 8192;
constexpr int kQL   = 8;
constexpr int kHID  = 1024;
constexpr int kNH   = 16;
constexpr int kNKV  = 8;
constexpr int kHD   = 64;
constexpr int kINTER= 4096;
constexpr int kK2   = 2 * kQL;       // 16 keys per edge
constexpr int kHQ   = kNH * kQL;     // 128 (head,query) pairs

// ---------- ordered-float encoding for atomicMax on floats ----------
__device__ __forceinline__ unsigned fenc(float x) {
  unsigned u = __float_as_uint(x);
  return (u & 0x80000000u) ? ~u : (u | 0x80000000u);
}
__device__ __forceinline__ float fdec(unsigned u) {
  unsigned v = (u & 0x80000000u) ? (u & 0x7fffffffu) : ~u;
  return __uint_as_float(v);
}

// ---------- RoPE tables: ct/st[p][j], p<16, j<32 ----------
__global__ void rope_tables_kernel(float* __restrict__ ct, float* __restrict__ st) {
  int i = threadIdx.x;              // 512 threads
  int p = i >> 5, j = i & 31;
  float inv = expf(-((float)(2 * j) / 64.0f) * logf(10000.0f));
  float ang = (float)p * inv;
  ct[i] = cosf(ang);
  st[i] = sinf(ang);
}

__global__ void init_menc_kernel(unsigned* __restrict__ m, int n) {
  int i = blockIdx.x * blockDim.x + threadIdx.x;
  if (i < n) m[i] = 0x007FFFFFu;    // fenc(-inf)
}

// ---------- RMSNorm: one block per 1024-float row ----------
__global__ __launch_bounds__(256) void rmsnorm_kernel(
    const float* __restrict__ in, const float* __restrict__ w,
    float* __restrict__ out) {
  __shared__ float red[4];
  int row = blockIdx.x, tid = threadIdx.x;
  const float* p = in + (size_t)row * kHID + tid * 4;
  float4 v = *(const float4*)p;
  float ss = v.x*v.x + v.y*v.y + v.z*v.z + v.w*v.w;
  #pragma unroll
  for (int off = 32; off > 0; off >>= 1) ss += __shfl_down(ss, off);
  int lane = tid & 63, wv = tid >> 6;
  if (lane == 0) red[wv] = ss;
  __syncthreads();
  float tot = red[0] + red[1] + red[2] + red[3];
  float rn = rsqrtf(tot * (1.0f / (float)kHID) + 1e-6f);
  float4 w4 = *(const float4*)(w + tid * 4);
  float4 o = make_float4(v.x*rn*w4.x, v.y*rn*w4.y, v.z*rn*w4.z, v.w*rn*w4.w);
  *(float4*)(out + (size_t)row * kHID + tid * 4) = o;
}

// ---------- fp32 GEMM: C[M,N] = A[M,K] * B[N,K]^T (+resid) ----------
// 128x128 tile, BK=16, 256 threads, 8x8 per thread.
__global__ __launch_bounds__(256) void gemm_bt_f32(
    const float* __restrict__ A, const float* __restrict__ B,
    const float* __restrict__ resid, float* __restrict__ C,
    int M, int N, int K) {
  __shared__ __align__(16) float As[16][132];
  __shared__ __align__(16) float Bs[16][132];
  const int tid = threadIdx.x;
  const int m0 = blockIdx.y * 128, n0 = blockIdx.x * 128;
  const int tx = tid & 15, ty = tid >> 4;
  const int lrow = tid >> 2;          // 0..63
  const int lk = (tid & 3) * 4;       // 0,4,8,12
  const float* Ap = A + (size_t)(m0 + lrow) * K + lk;
  const float* Bp = B + (size_t)(n0 + lrow) * K + lk;
  const size_t rowK64 = (size_t)64 * K;
  float acc[8][8];
  #pragma unroll
  for (int i = 0; i < 8; ++i)
    #pragma unroll
    for (int j = 0; j < 8; ++j) acc[i][j] = 0.0f;

  for (int k0 = 0; k0 < K; k0 += 16) {
    float4 a0 = *(const float4*)(Ap + k0);
    float4 a1 = *(const float4*)(Ap + rowK64 + k0);
    float4 b0 = *(const float4*)(Bp + k0);
    float4 b1 = *(const float4*)(Bp + rowK64 + k0);
    __syncthreads();
    As[lk+0][lrow] = a0.x; As[lk+1][lrow] = a0.y; As[lk+2][lrow] = a0.z; As[lk+3][lrow] = a0.w;
    As[lk+0][lrow+64] = a1.x; As[lk+1][lrow+64] = a1.y; As[lk+2][lrow+64] = a1.z; As[lk+3][lrow+64] = a1.w;
    Bs[lk+0][lrow] = b0.x; Bs[lk+1][lrow] = b0.y; Bs[lk+2][lrow] = b0.z; Bs[lk+3][lrow] = b0.w;
    Bs[lk+0][lrow+64] = b1.x; Bs[lk+1][lrow+64] = b1.y; Bs[lk+2][lrow+64] = b1.z; Bs[lk+3][lrow+64] = b1.w;
    __syncthreads();
    #pragma unroll
    for (int kk = 0; kk < 16; ++kk) {
      float4 va0 = *(const float4*)&As[kk][ty*8];
      float4 va1 = *(const float4*)&As[kk][ty*8+4];
      float4 vb0 = *(const float4*)&Bs[kk][tx*8];
      float4 vb1 = *(const float4*)&Bs[kk][tx*8+4];
      float av[8] = {va0.x,va0.y,va0.z,va0.w,va1.x,va1.y,va1.z,va1.w};
      float bv[8] = {vb0.x,vb0.y,vb0.z,vb0.w,vb1.x,vb1.y,vb1.z,vb1.w};
      #pragma unroll
      for (int i = 0; i < 8; ++i)
        #pragma unroll
        for (int j = 0; j < 8; ++j)
          acc[i][j] = fmaf(av[i], bv[j], acc[i][j]);
    }
  }
  #pragma unroll
  for (int i = 0; i < 8; ++i) {
    size_t row = (size_t)(m0 + ty*8 + i);
    float* Cp = C + row * N + n0 + tx*8;
    if (resid) {
      const float* Rp = resid + row * N + n0 + tx*8;
      float4 r0 = *(const float4*)Rp;
      float4 r1 = *(const float4*)(Rp + 4);
      *(float4*)Cp     = make_float4(acc[i][0]+r0.x, acc[i][1]+r0.y, acc[i][2]+r0.z, acc[i][3]+r0.w);
      *(float4*)(Cp+4) = make_float4(acc[i][4]+r1.x, acc[i][5]+r1.y, acc[i][6]+r1.z, acc[i][7]+r1.w);
    } else {
      *(float4*)Cp     = make_float4(acc[i][0], acc[i][1], acc[i][2], acc[i][3]);
      *(float4*)(Cp+4) = make_float4(acc[i][4], acc[i][5], acc[i][6], acc[i][7]);
    }
  }
}

// ---------- Pass A: per-edge logits + segment max ----------
// block = 256 threads, one block per edge.
__global__ __launch_bounds__(256) void attn_logits_kernel(
    const float* __restrict__ qbuf,   // (N*QL, 1024)
    const float* __restrict__ kbuf,   // (N*QL, 512)
    const float* __restrict__ ekbuf,  // (E*QL, 512)
    const int* __restrict__ srcIdx, const int* __restrict__ dstIdx,
    const float* __restrict__ ct, const float* __restrict__ st,
    float* __restrict__ logits,       // (E,16,8,16)
    unsigned* __restrict__ menc) {    // (N,128)
  __shared__ __align__(16) float ks[kK2][kNKV][kHD];  // 32 KB
  int e = blockIdx.x, tid = threadIdx.x;
  int srcn = srcIdx[e], dstn = dstIdx[e];
  // stage interleaved keys: ks[2t]=k[src,t], ks[2t+1]=ek[e,t]
  for (int i = tid; i < 2048; i += 256) {
    int f = i * 4;
    int k2 = f >> 9, rem = f & 511, t = k2 >> 1;
    float4 v4 = (k2 & 1)
      ? *(const float4*)(ekbuf + ((size_t)e   * kQL + t) * 512 + rem)
      : *(const float4*)(kbuf  + ((size_t)srcn* kQL + t) * 512 + rem);
    *(float4*)(&ks[0][0][0] + f) = v4;
  }
  __syncthreads();
  // RoPE keys in place, position = k2
  for (int p = tid; p < kK2 * kNKV * 32; p += 256) {
    int k2 = p >> 8, rem = p & 255, kv = rem >> 5, d = rem & 31;
    float c = ct[k2*32 + d], s_ = st[k2*32 + d];
    float a = ks[k2][kv][d], b = ks[k2][kv][d + 32];
    ks[k2][kv][d]      = a * c - b * s_;
    ks[k2][kv][d + 32] = b * c + a * s_;
  }
  __syncthreads();
  // each thread: one (h,q), 8 k2 values; q row in registers with RoPE
  int myhq = tid >> 1;
  int h = myhq >> 3, q = myhq & 7, kv = h >> 1;
  int k2g = (tid & 1) * 8;
  float qr[kHD];
  const float* qsrc = qbuf + ((size_t)dstn * kQL + q) * kHID + h * kHD;
  #pragma unroll
  for (int d4 = 0; d4 < 16; ++d4) {
    float4 v4 = *(const float4*)(qsrc + d4 * 4);
    qr[d4*4+0] = v4.x; qr[d4*4+1] = v4.y; qr[d4*4+2] = v4.z; qr[d4*4+3] = v4.w;
  }
  #pragma unroll
  for (int d = 0; d < 32; ++d) {
    float c = ct[q*32 + d], s_ = st[q*32 + d];
    float a = qr[d], b = qr[d + 32];
    qr[d]      = a * c - b * s_;
    qr[d + 32] = b * c + a * s_;
  }
  float l[8];
  float maxv = -__builtin_inff();
  #pragma unroll
  for (int i = 0; i < 8; ++i) {
    int k2 = k2g + i;
    const float* kp = &ks[k2][kv][0];
    float sum = 0.0f;
    #pragma unroll
    for (int d = 0; d < kHD; ++d) sum = fmaf(qr[d], kp[d], sum);
    sum *= 0.125f;                 // 1/sqrt(HD)
    l[i] = sum;
    maxv = fmaxf(maxv, sum);
  }
  float* lp = logits + (((size_t)e * kNH + h) * kQL + q) * 16 + k2g;
  *(float4*)lp       = make_float4(l[0], l[1], l[2], l[3]);
  *(float4*)(lp + 4) = make_float4(l[4], l[5], l[6], l[7]);
  maxv = fmaxf(maxv, __shfl_xor(maxv, 1));
  if ((tid & 1) == 0)
    atomicMax(&menc[(size_t)dstn * kHQ + myhq], fenc(maxv));
}

// ---------- Pass B: exp, segment sum, numerator accumulation ----------
__global__ __launch_bounds__(256) void attn_av_kernel(
    const float* __restrict__ vbuf, const float* __restrict__ evbuf,
    const int* __restrict__ srcIdx, const int* __restrict__ dstIdx,
    const float* __restrict__ logits,
    const unsigned* __restrict__ menc,
    float* __restrict__ sbuf,        // (N,128)
    float* __restrict__ accbuf) {    // (N,16,8,64)
  __shared__ __align__(16) float vs[kK2][kNKV][68];  // padded rows
  __shared__ float exs[kK2][kHQ];
  int e = blockIdx.x, tid = threadIdx.x;
  int srcn = srcIdx[e], dstn = dstIdx[e];
  for (int i = tid; i < 2048; i += 256) {
    int f = i * 4;
    int k2 = f >> 9, rem = f & 511, kv = rem >> 6, d = rem & 63, t = k2 >> 1;
    float4 v4 = (k2 & 1)
      ? *(const float4*)(evbuf + ((size_t)e   * kQL + t) * 512 + rem)
      : *(const float4*)(vbuf  + ((size_t)srcn* kQL + t) * 512 + rem);
    *(float4*)&vs[k2][kv][d] = v4;
  }
  // exponentials + segment denominator
  int myhq = tid >> 1;
  int k2g = (tid & 1) * 8;
  float m = fdec(menc[(size_t)dstn * kHQ + myhq]);
  const float* lp = logits + (((size_t)e * kNH + (myhq >> 3)) * kQL + (myhq & 7)) * 16 + k2g;
  float4 l0 = *(const float4*)lp;
  float4 l1 = *(const float4*)(lp + 4);
  float le[8] = {l0.x,l0.y,l0.z,l0.w,l1.x,l1.y,l1.z,l1.w};
  float psum = 0.0f;
  #pragma unroll
  for (int i = 0; i < 8; ++i) {
    float ex = __expf(le[i] - m);
    exs[k2g + i][myhq] = ex;
    psum += ex;
  }
  psum += __shfl_xor(psum, 1);
  if ((tid & 1) == 0) atomicAdd(&sbuf[(size_t)dstn * kHQ + myhq], psum);
  __syncthreads();
  // numerator: thread -> (h, q, half of d)
  int h = tid >> 4, qq = (tid >> 1) & 7, dh = tid & 1;
  int dbase = dh * 32, kv = h >> 1, hq = h * 8 + qq;
  float4 accv[8];
  #pragma unroll
  for (int j = 0; j < 8; ++j) accv[j] = make_float4(0.f, 0.f, 0.f, 0.f);
  #pragma unroll
  for (int k2 = 0; k2 < kK2; ++k2) {
    float ex = exs[k2][hq];
    const float* vp = &vs[k2][kv][dbase];
    #pragma unroll
    for (int j = 0; j < 8; ++j) {
      float4 vv = *(const float4*)(vp + j * 4);
      accv[j].x = fmaf(ex, vv.x, accv[j].x);
      accv[j].y = fmaf(ex, vv.y, accv[j].y);
      accv[j].z = fmaf(ex, vv.z, accv[j].z);
      accv[j].w = fmaf(ex, vv.w, accv[j].w);
    }
  }
  float* ap = accbuf + (((size_t)dstn * kNH + h) * kQL + qq) * kHD + dbase;
  #pragma unroll
  for (int j = 0; j < 8; ++j) {
    atomicAdd(ap + j*4 + 0, accv[j].x);
    atomicAdd(ap + j*4 + 1, accv[j].y);
    atomicAdd(ap + j*4 + 2, accv[j].z);
    atomicAdd(ap + j*4 + 3, accv[j].w);
  }
}

// ---------- finalize: agg[n][q][h*64+d] = acc[n][h][q][d] / (s+1e-16) ----------
__global__ __launch_bounds__(256) void attn_finalize_kernel(
    const float* __restrict__ acc, const float* __restrict__ sbuf,
    float* __restrict__ agg) {
  size_t idx = (size_t)blockIdx.x * 256 + threadIdx.x;
  size_t f = idx * 4;
  int n = (int)(f >> 13);
  int rem = (int)(f & 8191);
  int qq = rem >> 10;
  int rem2 = rem & 1023;
  int h = rem2 >> 6, d = rem2 & 63;
  float s = sbuf[(size_t)n * kHQ + h * 8 + qq] + 1e-16f;
  float inv = 1.0f / s;
  float4 a = *(const float4*)(acc + (((size_t)n * kNH + h) * kQL + qq) * kHD + d);
  *(float4*)(agg + f) = make_float4(a.x*inv, a.y*inv, a.z*inv, a.w*inv);
}

// ---------- silu(g)*u elementwise, in place into g ----------
__global__ __launch_bounds__(256) void silu_mul_kernel(
    float* __restrict__ g, const float* __restrict__ u, size_t n4) {
  size_t i = (size_t)blockIdx.x * 256 + threadIdx.x;
  if (i >= n4) return;
  float4 gv = *(const float4*)(g + i * 4);
  float4 uv = *(const float4*)(u + i * 4);
  float4 o;
  o.x = gv.x / (1.0f + __expf(-gv.x)) * uv.x;
  o.y = gv.y / (1.0f + __expf(-gv.y)) * uv.y;
  o.z = gv.z / (1.0f + __expf(-gv.z)) * uv.z;
  o.w = gv.w / (1.0f + __expf(-gv.w)) * uv.w;
  *(float4*)(g + i * 4) = o;
}

extern "C" void kernel_launch(void* const* d_in, const int* in_sizes, int n_in,
                              void* d_out, int out_size, void* d_ws, size_t ws_size,
                              hipStream_t stream) {
  const float* hidden = (const float*)d_in[0];
  const int*   eidx   = (const int*)d_in[1];
  const float* ehid   = (const float*)d_in[2];
  const float* Wq     = (const float*)d_in[3];
  const float* Wk     = (const float*)d_in[4];
  const float* Wv     = (const float*)d_in[5];
  const float* Wo     = (const float*)d_in[6];
  const float* Wgate  = (const float*)d_in[7];
  const float* Wup    = (const float*)d_in[8];
  const float* Wdown  = (const float*)d_in[9];
  const float* ln1    = (const float*)d_in[10];
  const float* ln2    = (const float*)d_in[11];
  const int* srcIdx = eidx;
  const int* dstIdx = eidx + kE;

  float* ws = (float*)d_ws;
  constexpr size_t NQ  = (size_t)kN * kQL;      // 8192 rows
  constexpr size_t EQ  = (size_t)kE * kQL;      // 65536 rows
  constexpr size_t szX   = NQ * kHID;           // 8,388,608
  constexpr size_t szQ   = NQ * kHID;
  constexpr size_t szK   = NQ * (kNKV * kHD);   // 4,194,304
  constexpr size_t szEK  = EQ * (kNKV * kHD);   // 33,554,432
  constexpr size_t szLog = (size_t)kE * kNH * kQL * 16;  // 16,777,216
  constexpr size_t szS   = (size_t)kN * kHQ;    // 131,072
  constexpr size_t szAcc = (size_t)kN * kNH * kQL * kHD; // 8,388,608

  size_t off = 0;
  float* x      = ws + off; off += szX;
  float* qb     = ws + off; off += szQ;     // later reused as h2
  float* kb     = ws + off; off += szK;
  float* vb     = ws + off; off += szK;
  float* ekb    = ws + off; off += szEK;    // later reused as g
  float* evb    = ws + off; off += szEK;    // later reused as u
  float* logits = ws + off; off += szLog;   // later reused as h
  float* sbuf   = ws + off; off += szS;
  float* accbuf = ws + off; off += szAcc;
  unsigned* menc = (unsigned*)(ws + off); off += szS;
  float* ct     = ws + off; off += 1024;
  float* st     = ws + off; off += 1024;
  // aliases
  float* agg = x;       // x dead after q/k/v GEMMs
  float* h   = logits;  // logits dead after pass B
  float* h2  = qb;      // q dead after pass A
  float* g   = ekb;     // ek dead after pass A
  float* u   = evb;     // ev dead after pass B
  float* outp = (float*)d_out;

  // init
  rope_tables_kernel<<<1, 512, 0, stream>>>(ct, st);
  init_menc_kernel<<<(int)((szS + 255) / 256), 256, 0, stream>>>(menc, (int)szS);
  hipMemsetAsync(sbuf, 0, (szS + szAcc) * sizeof(float), stream);  // s and acc contiguous

  // x = rmsnorm(hidden, ln1)
  rmsnorm_kernel<<<(int)NQ, 256, 0, stream>>>(hidden, ln1, x);

  // projections
  gemm_bt_f32<<<dim3(kHID/128, NQ/128), 256, 0, stream>>>(x, Wq, nullptr, qb, (int)NQ, kHID, kHID);
  gemm_bt_f32<<<dim3(512/128,  NQ/128), 256, 0, stream>>>(x, Wk, nullptr, kb, (int)NQ, 512, kHID);
  gemm_bt_f32<<<dim3(512/128,  NQ/128), 256, 0, stream>>>(x, Wv, nullptr, vb, (int)NQ, 512, kHID);
  gemm_bt_f32<<<dim3(512/128,  EQ/128), 256, 0, stream>>>(ehid, Wk, nullptr, ekb, (int)EQ, 512, kHID);
  gemm_bt_f32<<<dim3(512/128,  EQ/128), 256, 0, stream>>>(ehid, Wv, nullptr, evb, (int)EQ, 512, kHID);

  // attention passes
  attn_logits_kernel<<<kE, 256, 0, stream>>>(qb, kb, ekb, srcIdx, dstIdx, ct, st, logits, menc);
  attn_av_kernel<<<kE, 256, 0, stream>>>(vb, evb, srcIdx, dstIdx, logits, menc, sbuf, accbuf);
  attn_finalize_kernel<<<(int)(szAcc / 4 / 256), 256, 0, stream>>>(accbuf, sbuf, agg);

  // h = hidden + agg @ Wo^T
  gemm_bt_f32<<<dim3(kHID/128, NQ/128), 256, 0, stream>>>(agg, Wo, hidden, h, (int)NQ, kHID, kHID);

  // MLP
  rmsnorm_kernel<<<(int)NQ, 256, 0, stream>>>(h, ln2, h2);
  gemm_bt_f32<<<dim3(kINTER/128, NQ/128), 256, 0, stream>>>(h2, Wgate, nullptr, g, (int)NQ, kINTER, kHID);
  gemm_bt_f32<<<dim3(kINTER/128, NQ/128), 256, 0, stream>>>(h2, Wup,   nullptr, u, (int)NQ, kINTER, kHID);
  silu_mul_kernel<<<(int)(NQ * kINTER / 4 / 256), 256, 0, stream>>>(g, u, NQ * kINTER / 4);
  gemm_bt_f32<<<dim3(kHID/128, NQ/128), 256, 0, stream>>>(g, Wdown, h, outp, (int)NQ, kHID, kINTER);
}

// Round 2
// 1180.910 us; speedup vs baseline: 7.4120x; 7.4120x over previous
//
#include <hip/hip_runtime.h>
#include <cstddef>
#include <cstdint>

constexpr int kN    = 1024;
constexpr int kE    = 8192;
constexpr int kQL   = 8;
constexpr int kHID  = 1024;
constexpr int kNH   = 16;
constexpr int kNKV  = 8;
constexpr int kHD   = 64;
constexpr int kINTER= 4096;

typedef __bf16 bf16x8 __attribute__((ext_vector_type(8)));
typedef float  f32x4  __attribute__((ext_vector_type(4)));
typedef unsigned short ushort8 __attribute__((ext_vector_type(8)));

__device__ __forceinline__ unsigned short f2bf(float f) {
  unsigned u = __float_as_uint(f);
  unsigned r = (u + 0x7FFFu + ((u >> 16) & 1u)) >> 16;
  return (unsigned short)r;
}
__device__ __forceinline__ float bf2f(unsigned short u) {
  return __uint_as_float((unsigned)u << 16);
}
__device__ __forceinline__ void gload_lds16(const void* g, void* l) {
  __builtin_amdgcn_global_load_lds(
      (const __attribute__((address_space(1))) void*)g,
      (__attribute__((address_space(3))) void*)l, 16, 0, 0);
}

// ---------- RoPE tables: ct/st[p][j], p<16, j<32 ----------
__global__ void rope_tables_kernel(float* __restrict__ ct, float* __restrict__ st) {
  int i = threadIdx.x;              // 512 threads
  int p = i >> 5, j = i & 31;
  float inv = expf(-((float)(2 * j) / 64.0f) * logf(10000.0f));
  float ang = (float)p * inv;
  ct[i] = cosf(ang);
  st[i] = sinf(ang);
}

// ---------- fp32 -> bf16 convert (8 elems/thread) ----------
__global__ __launch_bounds__(256) void cvt_kernel(
    const float* __restrict__ in, unsigned short* __restrict__ out, int n8) {
  int i = blockIdx.x * 256 + threadIdx.x;
  if (i >= n8) return;
  const float4* p = (const float4*)(in + (size_t)i * 8);
  float4 a = p[0], b = p[1];
  uint4 o;
  o.x = f2bf(a.x) | ((unsigned)f2bf(a.y) << 16);
  o.y = f2bf(a.z) | ((unsigned)f2bf(a.w) << 16);
  o.z = f2bf(b.x) | ((unsigned)f2bf(b.y) << 16);
  o.w = f2bf(b.z) | ((unsigned)f2bf(b.w) << 16);
  *(uint4*)(out + (size_t)i * 8) = o;
}

// ---------- RMSNorm: fp32 in -> bf16 out, one block per row ----------
__global__ __launch_bounds__(256) void rmsnorm_bf16_kernel(
    const float* __restrict__ in, const float* __restrict__ w,
    unsigned short* __restrict__ out) {
  __shared__ float red[4];
  int row = blockIdx.x, tid = threadIdx.x;
  const float* p = in + (size_t)row * kHID + tid * 4;
  float4 v = *(const float4*)p;
  float ss = v.x*v.x + v.y*v.y + v.z*v.z + v.w*v.w;
  #pragma unroll
  for (int off = 32; off > 0; off >>= 1) ss += __shfl_down(ss, off);
  int lane = tid & 63, wv = tid >> 6;
  if (lane == 0) red[wv] = ss;
  __syncthreads();
  float tot = red[0] + red[1] + red[2] + red[3];
  float rn = rsqrtf(tot * (1.0f / (float)kHID) + 1e-6f);
  float4 w4 = *(const float4*)(w + tid * 4);
  uint2 o;
  o.x = f2bf(v.x*rn*w4.x) | ((unsigned)f2bf(v.y*rn*w4.y) << 16);
  o.y = f2bf(v.z*rn*w4.z) | ((unsigned)f2bf(v.w*rn*w4.w) << 16);
  *(uint2*)(out + (size_t)row * kHID + tid * 4) = o;
}

// ---------- bf16 MFMA GEMM: C[M,N] = A[M,K]*B[N,K]^T (+resid) ----------
// 128x128 tile, BK=32, 256 threads (4 waves), wave -> 64x64 quadrant, 4x4 MFMA tiles.
template<bool OUT_BF16>
__global__ __launch_bounds__(256) void gemm_bf16_bt(
    const unsigned short* __restrict__ A, const unsigned short* __restrict__ B,
    const float* __restrict__ resid, void* __restrict__ Cout,
    int M, int N, int K) {
  __shared__ unsigned short As[128][32];
  __shared__ unsigned short Bs[128][32];
  const int tid = threadIdx.x;
  const int lane = tid & 63, wave = tid >> 6;
  const int m0 = blockIdx.y * 128, n0 = blockIdx.x * 128;
  const int wm = (wave >> 1) * 64, wn = (wave & 1) * 64;
  const int lrow = lane >> 2, lk8 = (lane & 3) * 8;
  const unsigned short* Ag = A + (size_t)(m0 + wave * 32 + lrow) * K + lk8;
  const unsigned short* Bg = B + (size_t)(n0 + wave * 32 + lrow) * K + lk8;
  const int frow = lane & 15, fk = (lane >> 4) * 8;
  f32x4 acc[4][4];
  #pragma unroll
  for (int i = 0; i < 4; ++i)
    #pragma unroll
    for (int j = 0; j < 4; ++j) acc[i][j] = (f32x4){0.f, 0.f, 0.f, 0.f};

  for (int k0 = 0; k0 < K; k0 += 32) {
    __syncthreads();
    gload_lds16(Ag + k0,                 &As[wave * 32][0]);
    gload_lds16(Ag + k0 + (size_t)16 * K, &As[wave * 32 + 16][0]);
    gload_lds16(Bg + k0,                 &Bs[wave * 32][0]);
    gload_lds16(Bg + k0 + (size_t)16 * K, &Bs[wave * 32 + 16][0]);
    __syncthreads();
    bf16x8 af[4], bf[4];
    #pragma unroll
    for (int i = 0; i < 4; ++i) af[i] = *(const bf16x8*)&As[wm + i * 16 + frow][fk];
    #pragma unroll
    for (int j = 0; j < 4; ++j) bf[j] = *(const bf16x8*)&Bs[wn + j * 16 + frow][fk];
    #pragma unroll
    for (int i = 0; i < 4; ++i)
      #pragma unroll
      for (int j = 0; j < 4; ++j)
        acc[i][j] = __builtin_amdgcn_mfma_f32_16x16x32_bf16(af[i], bf[j], acc[i][j], 0, 0, 0);
  }
  const int r0 = (lane >> 4) * 4, cc = lane & 15;
  #pragma unroll
  for (int i = 0; i < 4; ++i) {
    #pragma unroll
    for (int r = 0; r < 4; ++r) {
      size_t grow = (size_t)(m0 + wm + i * 16 + r0 + r);
      #pragma unroll
      for (int j = 0; j < 4; ++j) {
        size_t gi = grow * N + (n0 + wn + j * 16 + cc);
        float v = acc[i][j][r];
        if (resid) v += resid[gi];
        if (OUT_BF16) ((unsigned short*)Cout)[gi] = f2bf(v);
        else          ((float*)Cout)[gi] = v;
      }
    }
  }
}

// ---------- CSR build ----------
__global__ void csr_count_kernel(const int* __restrict__ dst, int* __restrict__ cnt) {
  int e = blockIdx.x * 256 + threadIdx.x;
  if (e < kE) atomicAdd(&cnt[dst[e]], 1);
}
__global__ __launch_bounds__(1024) void csr_scan_kernel(
    const int* __restrict__ cnt, int* __restrict__ start) {
  __shared__ int tmp[1024];
  int t = threadIdx.x;
  tmp[t] = cnt[t];
  __syncthreads();
  for (int off = 1; off < 1024; off <<= 1) {
    int add = (t >= off) ? tmp[t - off] : 0;
    __syncthreads();
    tmp[t] += add;
    __syncthreads();
  }
  start[t + 1] = tmp[t];
  if (t == 0) start[0] = 0;
}
__global__ void csr_scatter_kernel(const int* __restrict__ dst, const int* __restrict__ start,
                                   int* __restrict__ cursor, int* __restrict__ elist) {
  int e = blockIdx.x * 256 + threadIdx.x;
  if (e < kE) {
    int d = dst[e];
    int pos = atomicAdd(&cursor[d], 1);
    elist[start[d] + pos] = e;
  }
}

// ---------- fused per-node attention: block per node, no atomics ----------
// thread -> (hq = tid>>1, half = tid&1); online softmax per (h,q) pair.
__global__ __launch_bounds__(256) void attn_fused_kernel(
    const float* __restrict__ qb,
    const unsigned short* __restrict__ kb, const unsigned short* __restrict__ vb,
    const unsigned short* __restrict__ ekb, const unsigned short* __restrict__ evb,
    const int* __restrict__ srcIdx, const int* __restrict__ elist,
    const int* __restrict__ start,
    const float* __restrict__ ct, const float* __restrict__ st,
    unsigned short* __restrict__ aggb) {
  __shared__ float ks[16][8][68];   // [k2][kv][d], pad 68 -> <=2-way conflicts
  __shared__ float vs[16][8][68];
  const int n = blockIdx.x, tid = threadIdx.x;
  const int hq = tid >> 1, h = hq >> 3, q = hq & 7, kv = h >> 1;
  const int half = tid & 1, k2g = half * 8, dbase = half * 32;

  // q row (RoPE'd) in registers — avoids 32-way LDS conflicts
  float qr[64];
  const float* qsrc = qb + ((size_t)n * kQL + q) * kHID + h * kHD;
  #pragma unroll
  for (int d4 = 0; d4 < 16; ++d4) {
    float4 v4 = *(const float4*)(qsrc + d4 * 4);
    qr[d4*4+0] = v4.x; qr[d4*4+1] = v4.y; qr[d4*4+2] = v4.z; qr[d4*4+3] = v4.w;
  }
  #pragma unroll
  for (int d = 0; d < 32; ++d) {
    float c = ct[q * 32 + d], s = st[q * 32 + d];
    float a = qr[d], b = qr[d + 32];
    qr[d] = a * c - b * s;
    qr[d + 32] = b * c + a * s;
  }

  float m = -3.4e38f, sh = 0.f;
  f32x4 accv[8];
  #pragma unroll
  for (int r = 0; r < 8; ++r) accv[r] = (f32x4){0.f, 0.f, 0.f, 0.f};

  const int s0 = start[n], s1 = start[n + 1];
  for (int jj = s0; jj < s1; ++jj) {
    const int e = elist[jj];
    const int srcn = srcIdx[e];
    __syncthreads();   // protect ks/vs from previous iteration's readers
    // stage K,V (bf16 global -> f32 LDS); k2=2t -> node row, k2=2t+1 -> edge row
    #pragma unroll
    for (int c = 0; c < 4; ++c) {
      int i = c * 256 + tid;          // 0..1023
      int f = i * 8;
      int k2 = f >> 9, rem = f & 511, t = k2 >> 1;
      int kvx = rem >> 6, d = rem & 63;
      const unsigned short* sk = (k2 & 1) ? ekb + ((size_t)e    * kQL + t) * 512 + rem
                                          : kb  + ((size_t)srcn * kQL + t) * 512 + rem;
      const unsigned short* sv = (k2 & 1) ? evb + ((size_t)e    * kQL + t) * 512 + rem
                                          : vb  + ((size_t)srcn * kQL + t) * 512 + rem;
      ushort8 uk = *(const ushort8*)sk;
      ushort8 uv = *(const ushort8*)sv;
      float* dk = &ks[k2][kvx][d];
      float* dv = &vs[k2][kvx][d];
      #pragma unroll
      for (int z = 0; z < 8; ++z) { dk[z] = bf2f(uk[z]); dv[z] = bf2f(uv[z]); }
    }
    __syncthreads();
    // RoPE keys in place (position = k2)
    #pragma unroll
    for (int c = 0; c < 16; ++c) {
      int p = c * 256 + tid;          // 0..4095
      int k2 = p >> 8, rem = p & 255, kvx = rem >> 5, d = rem & 31;
      float cc = ct[k2 * 32 + d], ss = st[k2 * 32 + d];
      float a = ks[k2][kvx][d], b = ks[k2][kvx][d + 32];
      ks[k2][kvx][d]      = a * cc - b * ss;
      ks[k2][kvx][d + 32] = b * cc + a * ss;
    }
    __syncthreads();
    // logits for my 8 k2 values
    float l[8];
    float lmax = -3.4e38f;
    #pragma unroll
    for (int i = 0; i < 8; ++i) {
      const float* kp = &ks[k2g + i][kv][0];
      float sum = 0.f;
      #pragma unroll
      for (int d = 0; d < 64; d += 4) {
        float4 kk = *(const float4*)(kp + d);
        sum = fmaf(qr[d+0], kk.x, sum);
        sum = fmaf(qr[d+1], kk.y, sum);
        sum = fmaf(qr[d+2], kk.z, sum);
        sum = fmaf(qr[d+3], kk.w, sum);
      }
      l[i] = sum * 0.125f;
      lmax = fmaxf(lmax, l[i]);
    }
    lmax = fmaxf(lmax, __shfl_xor(lmax, 1));   // pair max -> identical m in pair
    float mnew = fmaxf(m, lmax);
    float scale = __expf(m - mnew);
    float exo[8]; float ps = 0.f;
    #pragma unroll
    for (int i = 0; i < 8; ++i) { exo[i] = __expf(l[i] - mnew); ps += exo[i]; }
    sh = sh * scale + ps;
    m = mnew;
    #pragma unroll
    for (int r = 0; r < 8; ++r) accv[r] *= scale;
    float exp_[8];                               // partner's 8 exps
    #pragma unroll
    for (int i = 0; i < 8; ++i) exp_[i] = __shfl_xor(exo[i], 1);
    // AV: my d-half over all 16 k2
    #pragma unroll
    for (int k2 = 0; k2 < 16; ++k2) {
      float w = ((k2 >> 3) == half) ? exo[k2 & 7] : exp_[k2 & 7];
      const float* vp = &vs[k2][kv][dbase];
      #pragma unroll
      for (int r = 0; r < 8; ++r) {
        float4 vv = *(const float4*)(vp + r * 4);
        accv[r][0] = fmaf(w, vv.x, accv[r][0]);
        accv[r][1] = fmaf(w, vv.y, accv[r][1]);
        accv[r][2] = fmaf(w, vv.z, accv[r][2]);
        accv[r][3] = fmaf(w, vv.w, accv[r][3]);
      }
    }
  }
  float stot = sh + __shfl_xor(sh, 1);
  float inv = 1.f / (stot + 1e-16f);
  unsigned short* op = aggb + ((size_t)n * kQL + q) * kHID + h * kHD + dbase;
  #pragma unroll
  for (int r = 0; r < 8; ++r) {
    #pragma unroll
    for (int z = 0; z < 4; ++z) op[r * 4 + z] = f2bf(accv[r][z] * inv);
  }
}

// ---------- silu(g)*u -> bf16 ----------
__global__ __launch_bounds__(256) void silu_mul_kernel(
    const float* __restrict__ g, const float* __restrict__ u,
    unsigned short* __restrict__ out, int n4) {
  int i = blockIdx.x * 256 + threadIdx.x;
  if (i >= n4) return;
  float4 gv = *(const float4*)(g + (size_t)i * 4);
  float4 uv = *(const float4*)(u + (size_t)i * 4);
  float a = gv.x / (1.0f + __expf(-gv.x)) * uv.x;
  float b = gv.y / (1.0f + __expf(-gv.y)) * uv.y;
  float c = gv.z / (1.0f + __expf(-gv.z)) * uv.z;
  float d = gv.w / (1.0f + __expf(-gv.w)) * uv.w;
  uint2 o;
  o.x = f2bf(a) | ((unsigned)f2bf(b) << 16);
  o.y = f2bf(c) | ((unsigned)f2bf(d) << 16);
  *(uint2*)(out + (size_t)i * 4) = o;
}

extern "C" void kernel_launch(void* const* d_in, const int* in_sizes, int n_in,
                              void* d_out, int out_size, void* d_ws, size_t ws_size,
                              hipStream_t stream) {
  const float* hidden = (const float*)d_in[0];
  const int*   eidx   = (const int*)d_in[1];
  const float* ehid   = (const float*)d_in[2];
  const float* Wq     = (const float*)d_in[3];
  const float* Wk     = (const float*)d_in[4];
  const float* Wv     = (const float*)d_in[5];
  const float* Wo     = (const float*)d_in[6];
  const float* Wgate  = (const float*)d_in[7];
  const float* Wup    = (const float*)d_in[8];
  const float* Wdown  = (const float*)d_in[9];
  const float* ln1    = (const float*)d_in[10];
  const float* ln2    = (const float*)d_in[11];
  const int* srcIdx = eidx;
  const int* dstIdx = eidx + kE;

  char* wsb = (char*)d_ws;
  size_t off = 0;
  auto alloc = [&](size_t bytes) { char* p = wsb + off; off += (bytes + 255) & ~(size_t)255; return p; };
  // ORDER MATTERS: alias unions below depend on adjacency.
  unsigned short* x16   = (unsigned short*)alloc(16777216);   // [8192][1024] bf16
  float*          qb    = (float*)alloc(33554432);            // [8192][1024] f32
  unsigned short* kb16  = (unsigned short*)alloc(8388608);    // [8192][512]
  unsigned short* vb16  = (unsigned short*)alloc(8388608);
  unsigned short* ekb16 = (unsigned short*)alloc(67108864);   // [65536][512]
  unsigned short* evb16 = (unsigned short*)alloc(67108864);
  unsigned short* eh16  = (unsigned short*)alloc(134217728);  // [65536][1024]
  unsigned short* wq16  = (unsigned short*)alloc(2097152);
  unsigned short* wk16  = (unsigned short*)alloc(1048576);
  unsigned short* wv16  = (unsigned short*)alloc(1048576);
  unsigned short* wo16  = (unsigned short*)alloc(2097152);
  unsigned short* wg16  = (unsigned short*)alloc(8388608);
  unsigned short* wu16  = (unsigned short*)alloc(8388608);
  unsigned short* wd16  = (unsigned short*)alloc(8388608);
  unsigned short* agg16 = (unsigned short*)alloc(16777216);   // [8192][1024]
  float*          hbuf  = (float*)alloc(33554432);            // [8192][1024] f32
  unsigned short* h216  = (unsigned short*)alloc(16777216);
  int* cnt    = (int*)alloc(4096);
  int* cursor = (int*)alloc(4096);   // adjacent to cnt -> one memset
  int* startb = (int*)alloc(4352);   // 1025 ints
  int* elist  = (int*)alloc(32768);
  float* ct   = (float*)alloc(2048);
  float* st   = (float*)alloc(2048);
  // aliases (exact-size unions; lifetimes verified):
  float* g  = (float*)eh16;                 // gate out overlays ehid_bf16 (dead after ek/ev GEMMs)
  float* u  = (float*)ekb16;                // up out overlays ekb16+evb16 (dead after attention)
  unsigned short* gm16 = x16;               // silu out overlays x16+qb+kb16+vb16 (dead after attention)
  float* outp = (float*)d_out;

  hipMemsetAsync(cnt, 0, 8192, stream);     // cnt + cursor
  rope_tables_kernel<<<1, 512, 0, stream>>>(ct, st);

  // fp32 -> bf16 conversions
  cvt_kernel<<<32768, 256, 0, stream>>>(ehid,  eh16, 8388608);
  cvt_kernel<<<512,   256, 0, stream>>>(Wq,    wq16, 131072);
  cvt_kernel<<<256,   256, 0, stream>>>(Wk,    wk16, 65536);
  cvt_kernel<<<256,   256, 0, stream>>>(Wv,    wv16, 65536);
  cvt_kernel<<<512,   256, 0, stream>>>(Wo,    wo16, 131072);
  cvt_kernel<<<2048,  256, 0, stream>>>(Wgate, wg16, 524288);
  cvt_kernel<<<2048,  256, 0, stream>>>(Wup,   wu16, 524288);
  cvt_kernel<<<2048,  256, 0, stream>>>(Wdown, wd16, 524288);

  // CSR build
  csr_count_kernel<<<32, 256, 0, stream>>>(dstIdx, cnt);
  csr_scan_kernel<<<1, 1024, 0, stream>>>(cnt, startb);
  csr_scatter_kernel<<<32, 256, 0, stream>>>(dstIdx, startb, cursor, elist);

  // x = rmsnorm(hidden, ln1) -> bf16
  rmsnorm_bf16_kernel<<<kN * kQL, 256, 0, stream>>>(hidden, ln1, x16);

  // projections (MFMA bf16)
  gemm_bf16_bt<false><<<dim3(8, 64),  256, 0, stream>>>(x16,  wq16, nullptr, qb,    8192, 1024, 1024);
  gemm_bf16_bt<true ><<<dim3(4, 64),  256, 0, stream>>>(x16,  wk16, nullptr, kb16,  8192,  512, 1024);
  gemm_bf16_bt<true ><<<dim3(4, 64),  256, 0, stream>>>(x16,  wv16, nullptr, vb16,  8192,  512, 1024);
  gemm_bf16_bt<true ><<<dim3(4, 512), 256, 0, stream>>>(eh16, wk16, nullptr, ekb16, 65536, 512, 1024);
  gemm_bf16_bt<true ><<<dim3(4, 512), 256, 0, stream>>>(eh16, wv16, nullptr, evb16, 65536, 512, 1024);

  // fused graph attention (no atomics)
  attn_fused_kernel<<<kN, 256, 0, stream>>>(qb, kb16, vb16, ekb16, evb16,
                                            srcIdx, elist, startb, ct, st, agg16);

  // h = hidden + agg @ Wo^T
  gemm_bf16_bt<false><<<dim3(8, 64), 256, 0, stream>>>(agg16, wo16, hidden, hbuf, 8192, 1024, 1024);

  // MLP
  rmsnorm_bf16_kernel<<<kN * kQL, 256, 0, stream>>>(hbuf, ln2, h216);
  gemm_bf16_bt<false><<<dim3(32, 64), 256, 0, stream>>>(h216, wg16, nullptr, g, 8192, 4096, 1024);
  gemm_bf16_bt<false><<<dim3(32, 64), 256, 0, stream>>>(h216, wu16, nullptr, u, 8192, 4096, 1024);
  silu_mul_kernel<<<32768, 256, 0, stream>>>(g, u, gm16, 8388608);
  gemm_bf16_bt<false><<<dim3(8, 64), 256, 0, stream>>>(gm16, wd16, hbuf, outp, 8192, 1024, 4096);
}

// Round 3
// 1010.664 us; speedup vs baseline: 8.6606x; 1.1684x over previous
//
#include <hip/hip_runtime.h>
#include <cstddef>
#include <cstdint>

constexpr int kN    = 1024;
constexpr int kE    = 8192;
constexpr int kQL   = 8;
constexpr int kHID  = 1024;
constexpr int kINTER= 4096;

typedef __bf16 bf16x8 __attribute__((ext_vector_type(8)));
typedef float  f32x4  __attribute__((ext_vector_type(4)));
typedef unsigned short ushort8 __attribute__((ext_vector_type(8)));

__device__ __forceinline__ unsigned short f2bf(float f) {
  unsigned u = __float_as_uint(f);
  unsigned r = (u + 0x7FFFu + ((u >> 16) & 1u)) >> 16;
  return (unsigned short)r;
}
__device__ __forceinline__ float bf2f(unsigned short u) {
  return __uint_as_float((unsigned)u << 16);
}
__device__ __forceinline__ unsigned pkbf(float a, float b) {
  return (unsigned)f2bf(a) | ((unsigned)f2bf(b) << 16);
}
__device__ __forceinline__ void gload_lds16(const void* g, void* l) {
  __builtin_amdgcn_global_load_lds(
      (const __attribute__((address_space(1))) void*)g,
      (__attribute__((address_space(3))) void*)l, 16, 0, 0);
}

// ---------- RoPE tables: ct/st[p][j], p<16, j<32 ----------
__global__ void rope_tables_kernel(float* __restrict__ ct, float* __restrict__ st) {
  int i = threadIdx.x;              // 512 threads
  int p = i >> 5, j = i & 31;
  float inv = expf(-((float)(2 * j) / 64.0f) * logf(10000.0f));
  float ang = (float)p * inv;
  ct[i] = cosf(ang);
  st[i] = sinf(ang);
}

// ---------- fp32 -> bf16 convert (8 elems/thread) ----------
__global__ __launch_bounds__(256) void cvt_kernel(
    const float* __restrict__ in, unsigned short* __restrict__ out, int n8) {
  int i = blockIdx.x * 256 + threadIdx.x;
  if (i >= n8) return;
  const float4* p = (const float4*)(in + (size_t)i * 8);
  float4 a = p[0], b = p[1];
  uint4 o;
  o.x = f2bf(a.x) | ((unsigned)f2bf(a.y) << 16);
  o.y = f2bf(a.z) | ((unsigned)f2bf(a.w) << 16);
  o.z = f2bf(b.x) | ((unsigned)f2bf(b.y) << 16);
  o.w = f2bf(b.z) | ((unsigned)f2bf(b.w) << 16);
  *(uint4*)(out + (size_t)i * 8) = o;
}

// ---------- RMSNorm: fp32 in -> bf16 out, one block per row ----------
__global__ __launch_bounds__(256) void rmsnorm_bf16_kernel(
    const float* __restrict__ in, const float* __restrict__ w,
    unsigned short* __restrict__ out) {
  __shared__ float red[4];
  int row = blockIdx.x, tid = threadIdx.x;
  const float* p = in + (size_t)row * kHID + tid * 4;
  float4 v = *(const float4*)p;
  float ss = v.x*v.x + v.y*v.y + v.z*v.z + v.w*v.w;
  #pragma unroll
  for (int off = 32; off > 0; off >>= 1) ss += __shfl_down(ss, off);
  int lane = tid & 63, wv = tid >> 6;
  if (lane == 0) red[wv] = ss;
  __syncthreads();
  float tot = red[0] + red[1] + red[2] + red[3];
  float rn = rsqrtf(tot * (1.0f / (float)kHID) + 1e-6f);
  float4 w4 = *(const float4*)(w + tid * 4);
  uint2 o;
  o.x = f2bf(v.x*rn*w4.x) | ((unsigned)f2bf(v.y*rn*w4.y) << 16);
  o.y = f2bf(v.z*rn*w4.z) | ((unsigned)f2bf(v.w*rn*w4.w) << 16);
  *(uint2*)(out + (size_t)row * kHID + tid * 4) = o;
}

// ---------- bf16 MFMA GEMM: C[M,N] = A[M,K]*B[N,K]^T (+resid) ----------
template<bool OUT_BF16>
__global__ __launch_bounds__(256) void gemm_bf16_bt(
    const unsigned short* __restrict__ A, const unsigned short* __restrict__ B,
    const float* __restrict__ resid, void* __restrict__ Cout,
    int M, int N, int K) {
  __shared__ unsigned short As[128][32];
  __shared__ unsigned short Bs[128][32];
  const int tid = threadIdx.x;
  const int lane = tid & 63, wave = tid >> 6;
  const int m0 = blockIdx.y * 128, n0 = blockIdx.x * 128;
  const int wm = (wave >> 1) * 64, wn = (wave & 1) * 64;
  const int lrow = lane >> 2, lk8 = (lane & 3) * 8;
  const unsigned short* Ag = A + (size_t)(m0 + wave * 32 + lrow) * K + lk8;
  const unsigned short* Bg = B + (size_t)(n0 + wave * 32 + lrow) * K + lk8;
  const int frow = lane & 15, fk = (lane >> 4) * 8;
  f32x4 acc[4][4];
  #pragma unroll
  for (int i = 0; i < 4; ++i)
    #pragma unroll
    for (int j = 0; j < 4; ++j) acc[i][j] = (f32x4){0.f, 0.f, 0.f, 0.f};

  for (int k0 = 0; k0 < K; k0 += 32) {
    __syncthreads();
    gload_lds16(Ag + k0,                 &As[wave * 32][0]);
    gload_lds16(Ag + k0 + (size_t)16 * K, &As[wave * 32 + 16][0]);
    gload_lds16(Bg + k0,                 &Bs[wave * 32][0]);
    gload_lds16(Bg + k0 + (size_t)16 * K, &Bs[wave * 32 + 16][0]);
    __syncthreads();
    bf16x8 af[4], bf[4];
    #pragma unroll
    for (int i = 0; i < 4; ++i) af[i] = *(const bf16x8*)&As[wm + i * 16 + frow][fk];
    #pragma unroll
    for (int j = 0; j < 4; ++j) bf[j] = *(const bf16x8*)&Bs[wn + j * 16 + frow][fk];
    #pragma unroll
    for (int i = 0; i < 4; ++i)
      #pragma unroll
      for (int j = 0; j < 4; ++j)
        acc[i][j] = __builtin_amdgcn_mfma_f32_16x16x32_bf16(af[i], bf[j], acc[i][j], 0, 0, 0);
  }
  const int r0 = (lane >> 4) * 4, cc = lane & 15;
  #pragma unroll
  for (int i = 0; i < 4; ++i) {
    #pragma unroll
    for (int r = 0; r < 4; ++r) {
      size_t grow = (size_t)(m0 + wm + i * 16 + r0 + r);
      #pragma unroll
      for (int j = 0; j < 4; ++j) {
        size_t gi = grow * N + (n0 + wn + j * 16 + cc);
        float v = acc[i][j][r];
        if (resid) v += resid[gi];
        if (OUT_BF16) ((unsigned short*)Cout)[gi] = f2bf(v);
        else          ((float*)Cout)[gi] = v;
      }
    }
  }
}

// ---------- CSR build ----------
__global__ void csr_count_kernel(const int* __restrict__ dst, int* __restrict__ cnt) {
  int e = blockIdx.x * 256 + threadIdx.x;
  if (e < kE) atomicAdd(&cnt[dst[e]], 1);
}
__global__ __launch_bounds__(1024) void csr_scan_kernel(
    const int* __restrict__ cnt, int* __restrict__ start) {
  __shared__ int tmp[1024];
  int t = threadIdx.x;
  tmp[t] = cnt[t];
  __syncthreads();
  for (int off = 1; off < 1024; off <<= 1) {
    int add = (t >= off) ? tmp[t - off] : 0;
    __syncthreads();
    tmp[t] += add;
    __syncthreads();
  }
  start[t + 1] = tmp[t];
  if (t == 0) start[0] = 0;
}
__global__ void csr_scatter_kernel(const int* __restrict__ dst, const int* __restrict__ start,
                                   int* __restrict__ cursor, int* __restrict__ elist) {
  int e = blockIdx.x * 256 + threadIdx.x;
  if (e < kE) {
    int d = dst[e];
    int pos = atomicAdd(&cursor[d], 1);
    elist[start[d] + pos] = e;
  }
}

// ---------- in-place RoPE on K buffers (bf16) ----------
// buf rows of 512 = 8 kv-heads x 64; position = 2*(row&7) + posOdd.
__global__ __launch_bounds__(256) void rope_k_kernel(
    unsigned short* __restrict__ buf, int posOdd, int nrows,
    const float* __restrict__ ct, const float* __restrict__ st) {
  int tid = blockIdx.x * 256 + threadIdx.x;
  int row = tid >> 5;
  if (row >= nrows) return;
  int t32 = tid & 31, kv = t32 >> 2, dq = (t32 & 3) * 8;
  int pos = 2 * (row & 7) + posOdd;
  unsigned short* p = buf + (size_t)row * 512 + kv * 64 + dq;
  ushort8 lo = *(ushort8*)p, hi = *(ushort8*)(p + 32);
  const float* cp = ct + pos * 32 + dq;
  const float* sp = st + pos * 32 + dq;
  ushort8 olo, ohi;
  #pragma unroll
  for (int z = 0; z < 8; ++z) {
    float a = bf2f(lo[z]), b = bf2f(hi[z]);
    float c = cp[z], s = sp[z];
    olo[z] = f2bf(a * c - b * s);
    ohi[z] = f2bf(b * c + a * s);
  }
  *(ushort8*)p = olo;
  *(ushort8*)(p + 32) = ohi;
}

// ---------- in-place RoPE on Q buffer (bf16, rows of 1024 = 16 h x 64) ----------
__global__ __launch_bounds__(256) void rope_q_kernel(
    unsigned short* __restrict__ buf,
    const float* __restrict__ ct, const float* __restrict__ st) {
  int tid = blockIdx.x * 256 + threadIdx.x;
  int row = tid >> 6;                // 8192 rows, 64 threads/row
  int t64 = tid & 63, h = t64 >> 2, dq = (t64 & 3) * 8;
  int pos = row & 7;
  unsigned short* p = buf + (size_t)row * 1024 + h * 64 + dq;
  ushort8 lo = *(ushort8*)p, hi = *(ushort8*)(p + 32);
  const float* cp = ct + pos * 32 + dq;
  const float* sp = st + pos * 32 + dq;
  ushort8 olo, ohi;
  #pragma unroll
  for (int z = 0; z < 8; ++z) {
    float a = bf2f(lo[z]), b = bf2f(hi[z]);
    float c = cp[z], s = sp[z];
    olo[z] = f2bf(a * c - b * s);
    ohi[z] = f2bf(b * c + a * s);
  }
  *(ushort8*)p = olo;
  *(ushort8*)(p + 32) = ohi;
}

// ---------- MFMA graph attention: one wave per (node, kv-head) ----------
// 2048 blocks x 256 threads; wave w of block b handles n=b>>1, g=(b&1)*4+w.
// Swapped QK^T: S^T[k2][hq] via mfma(K,Q); online softmax per hq (lane-col);
// edge-paired PV via one K=32 mfma per 16-col d tile.
__global__ __launch_bounds__(256) void attn_mfma_kernel(
    const unsigned short* __restrict__ qb,   // roped (8192,1024)
    const unsigned short* __restrict__ kb,   // roped (8192,512)
    const unsigned short* __restrict__ vb,   // (8192,512)
    const unsigned short* __restrict__ ekb,  // roped (65536,512)
    const unsigned short* __restrict__ evb,  // (65536,512)
    const int* __restrict__ srcIdx, const int* __restrict__ elist,
    const int* __restrict__ start,
    unsigned short* __restrict__ aggb) {
  const int n = blockIdx.x >> 1;
  const int g = (blockIdx.x & 1) * 4 + (threadIdx.x >> 6);
  const int lane = threadIdx.x & 63;
  const int l15 = lane & 15, lg = lane >> 4;

  // Q fragment (B-operand): col(hq)=l15, k(d)=lg*8+j (+32 for second mfma)
  const int h = g * 2 + (l15 >> 3), q = l15 & 7;
  const unsigned short* qrow = qb + ((size_t)n * 8 + q) * 1024 + h * 64 + lg * 8;
  const bf16x8 qf0 = *(const bf16x8*)qrow;
  const bf16x8 qf1 = *(const bf16x8*)(qrow + 32);

  float m = -3.4e38f, sh = 0.f;
  f32x4 oacc[4];
  #pragma unroll
  for (int t = 0; t < 4; ++t) oacc[t] = (f32x4){0.f, 0.f, 0.f, 0.f};

  const int kparity = l15 & 1;         // k2 odd -> edge K row
  const int t_ = l15 >> 1;
  const int lgh = lg & 1;              // which 8-k2 half my PV k-slice covers
  const int eS = lg >> 1;              // which edge my PV k-slice covers

  const int s0 = start[n], s1 = start[n + 1];
  for (int jj = s0; jj < s1; jj += 2) {
    const int e0 = elist[jj];
    const bool has1 = (jj + 1 < s1);
    const int e1 = has1 ? elist[jj + 1] : e0;
    const int sn0 = srcIdx[e0], sn1 = srcIdx[e1];

    // K fragments (A-operand): row(k2)=l15, k(d)=lg*8+j
    const unsigned short* kr0 = kparity
        ? ekb + ((size_t)e0 * 8 + t_) * 512 + g * 64 + lg * 8
        : kb  + ((size_t)sn0 * 8 + t_) * 512 + g * 64 + lg * 8;
    const unsigned short* kr1 = kparity
        ? ekb + ((size_t)e1 * 8 + t_) * 512 + g * 64 + lg * 8
        : kb  + ((size_t)sn1 * 8 + t_) * 512 + g * 64 + lg * 8;
    bf16x8 ka0 = *(const bf16x8*)kr0, ka1 = *(const bf16x8*)(kr0 + 32);
    bf16x8 kc0 = *(const bf16x8*)kr1, kc1 = *(const bf16x8*)(kr1 + 32);

    // V B-operand source rows for my k-slice (k2 = lgh*8 + j)
    const int   evsel = eS ? e1 : e0;
    const int   snsel = eS ? sn1 : sn0;
    const unsigned short* vn = vb  + ((size_t)snsel * 8 + lgh * 4) * 512 + g * 64;
    const unsigned short* ve = evb + ((size_t)evsel * 8 + lgh * 4) * 512 + g * 64;

    f32x4 z = (f32x4){0.f, 0.f, 0.f, 0.f};
    f32x4 sa = __builtin_amdgcn_mfma_f32_16x16x32_bf16(ka0, qf0, z, 0, 0, 0);
    sa       = __builtin_amdgcn_mfma_f32_16x16x32_bf16(ka1, qf1, sa, 0, 0, 0);
    f32x4 sb = __builtin_amdgcn_mfma_f32_16x16x32_bf16(kc0, qf0, z, 0, 0, 0);
    sb       = __builtin_amdgcn_mfma_f32_16x16x32_bf16(kc1, qf1, sb, 0, 0, 0);

    float l0[4], l1[4];
    float lmax = -3.4e38f;
    #pragma unroll
    for (int r = 0; r < 4; ++r) {
      l0[r] = sa[r] * 0.125f;
      l1[r] = has1 ? sb[r] * 0.125f : -3.4e38f;
      lmax = fmaxf(lmax, fmaxf(l0[r], l1[r]));
    }
    lmax = fmaxf(lmax, __shfl_xor(lmax, 16));
    lmax = fmaxf(lmax, __shfl_xor(lmax, 32));
    const float mnew = fmaxf(m, lmax);
    const float scale = __expf(m - mnew);
    float p0[4], p1[4], ps = 0.f;
    #pragma unroll
    for (int r = 0; r < 4; ++r) {
      p0[r] = __expf(l0[r] - mnew);
      p1[r] = __expf(l1[r] - mnew);
      ps += p0[r] + p1[r];
    }
    ps += __shfl_xor(ps, 16);
    ps += __shfl_xor(ps, 32);
    sh = sh * scale + ps;
    m = mnew;

    // rescale accumulated O rows (row hq' = lg*4+r; scale lives at lane l15==hq')
    #pragma unroll
    for (int r = 0; r < 4; ++r) {
      float sr = __shfl(scale, lg * 4 + r);
      #pragma unroll
      for (int t = 0; t < 4; ++t) oacc[t][r] *= sr;
    }

    // redistribute P (S^T C-layout) -> A-frag layout for PV
    unsigned w00 = pkbf(p0[0], p0[1]), w01 = pkbf(p0[2], p0[3]);
    unsigned w10 = pkbf(p1[0], p1[1]), w11 = pkbf(p1[2], p1[3]);
    const int L1 = l15 + 32 * lgh, L2 = L1 + 16;
    unsigned a0 = __shfl(w00, L1), a1 = __shfl(w01, L1);
    unsigned a2 = __shfl(w00, L2), a3 = __shfl(w01, L2);
    unsigned b0 = __shfl(w10, L1), b1 = __shfl(w11, L1);
    unsigned b2 = __shfl(w10, L2), b3 = __shfl(w11, L2);
    uint4 wv;
    wv.x = eS ? b0 : a0; wv.y = eS ? b1 : a1;
    wv.z = eS ? b2 : a2; wv.w = eS ? b3 : a3;
    const bf16x8 pf = __builtin_bit_cast(bf16x8, wv);

    // PV: one mfma per 16-wide d tile, K=32 covers both edges
    #pragma unroll
    for (int t = 0; t < 4; ++t) {
      const int col = t * 16 + l15;
      ushort8 vr;
      #pragma unroll
      for (int j = 0; j < 8; ++j) {
        const unsigned short* srcp = (j & 1) ? ve : vn;
        vr[j] = srcp[(j >> 1) * 512 + col];
      }
      const bf16x8 vf = __builtin_bit_cast(bf16x8, vr);
      oacc[t] = __builtin_amdgcn_mfma_f32_16x16x32_bf16(pf, vf, oacc[t], 0, 0, 0);
    }
  }

  // finalize: divide row hq'=lg*4+r by its softmax sum, write bf16
  #pragma unroll
  for (int r = 0; r < 4; ++r) {
    const float sr = __shfl(sh, lg * 4 + r);
    const float inv = 1.f / (sr + 1e-16f);
    const int hq = lg * 4 + r;
    const int hh = g * 2 + (hq >> 3), qq = hq & 7;
    unsigned short* op = aggb + ((size_t)n * 8 + qq) * 1024 + hh * 64 + l15;
    #pragma unroll
    for (int t = 0; t < 4; ++t) op[t * 16] = f2bf(oacc[t][r] * inv);
  }
}

// ---------- silu(g)*u -> bf16 ----------
__global__ __launch_bounds__(256) void silu_mul_kernel(
    const float* __restrict__ g, const float* __restrict__ u,
    unsigned short* __restrict__ out, int n4) {
  int i = blockIdx.x * 256 + threadIdx.x;
  if (i >= n4) return;
  float4 gv = *(const float4*)(g + (size_t)i * 4);
  float4 uv = *(const float4*)(u + (size_t)i * 4);
  float a = gv.x / (1.0f + __expf(-gv.x)) * uv.x;
  float b = gv.y / (1.0f + __expf(-gv.y)) * uv.y;
  float c = gv.z / (1.0f + __expf(-gv.z)) * uv.z;
  float d = gv.w / (1.0f + __expf(-gv.w)) * uv.w;
  uint2 o;
  o.x = f2bf(a) | ((unsigned)f2bf(b) << 16);
  o.y = f2bf(c) | ((unsigned)f2bf(d) << 16);
  *(uint2*)(out + (size_t)i * 4) = o;
}

extern "C" void kernel_launch(void* const* d_in, const int* in_sizes, int n_in,
                              void* d_out, int out_size, void* d_ws, size_t ws_size,
                              hipStream_t stream) {
  const float* hidden = (const float*)d_in[0];
  const int*   eidx   = (const int*)d_in[1];
  const float* ehid   = (const float*)d_in[2];
  const float* Wq     = (const float*)d_in[3];
  const float* Wk     = (const float*)d_in[4];
  const float* Wv     = (const float*)d_in[5];
  const float* Wo     = (const float*)d_in[6];
  const float* Wgate  = (const float*)d_in[7];
  const float* Wup    = (const float*)d_in[8];
  const float* Wdown  = (const float*)d_in[9];
  const float* ln1    = (const float*)d_in[10];
  const float* ln2    = (const float*)d_in[11];
  const int* srcIdx = eidx;
  const int* dstIdx = eidx + kE;

  char* wsb = (char*)d_ws;
  size_t off = 0;
  auto alloc = [&](size_t bytes) { char* p = wsb + off; off += (bytes + 255) & ~(size_t)255; return p; };
  unsigned short* x16   = (unsigned short*)alloc(16777216);   // [8192][1024] bf16
  unsigned short* qb16  = (unsigned short*)alloc(16777216);   // [8192][1024] bf16
  unsigned short* kb16  = (unsigned short*)alloc(8388608);    // [8192][512]
  unsigned short* vb16  = (unsigned short*)alloc(8388608);
  unsigned short* ekb16 = (unsigned short*)alloc(67108864);   // [65536][512]
  unsigned short* evb16 = (unsigned short*)alloc(67108864);
  unsigned short* eh16  = (unsigned short*)alloc(134217728);  // [65536][1024]
  unsigned short* wq16  = (unsigned short*)alloc(2097152);
  unsigned short* wk16  = (unsigned short*)alloc(1048576);
  unsigned short* wv16  = (unsigned short*)alloc(1048576);
  unsigned short* wo16  = (unsigned short*)alloc(2097152);
  unsigned short* wg16  = (unsigned short*)alloc(8388608);
  unsigned short* wu16  = (unsigned short*)alloc(8388608);
  unsigned short* wd16  = (unsigned short*)alloc(8388608);
  unsigned short* agg16 = (unsigned short*)alloc(16777216);   // [8192][1024]
  float*          hbuf  = (float*)alloc(33554432);            // [8192][1024] f32
  unsigned short* h216  = (unsigned short*)alloc(16777216);
  int* cnt    = (int*)alloc(4096);
  int* cursor = (int*)alloc(4096);   // adjacent to cnt -> one memset
  int* startb = (int*)alloc(4352);   // 1025 ints
  int* elist  = (int*)alloc(32768);
  float* ct   = (float*)alloc(2048);
  float* st   = (float*)alloc(2048);
  // aliases (lifetimes verified):
  float* g  = (float*)eh16;                 // gate out overlays eh16 (dead after ek/ev GEMMs)
  float* u  = (float*)ekb16;                // up out overlays ekb16(+evb16) (dead after attention)
  unsigned short* gm16 = x16;               // silu out overlays x16 (dead after gate/up GEMMs)
  float* outp = (float*)d_out;

  hipMemsetAsync(cnt, 0, 8192, stream);     // cnt + cursor
  rope_tables_kernel<<<1, 512, 0, stream>>>(ct, st);

  // fp32 -> bf16 conversions
  cvt_kernel<<<32768, 256, 0, stream>>>(ehid,  eh16, 8388608);
  cvt_kernel<<<512,   256, 0, stream>>>(Wq,    wq16, 131072);
  cvt_kernel<<<256,   256, 0, stream>>>(Wk,    wk16, 65536);
  cvt_kernel<<<256,   256, 0, stream>>>(Wv,    wv16, 65536);
  cvt_kernel<<<512,   256, 0, stream>>>(Wo,    wo16, 131072);
  cvt_kernel<<<2048,  256, 0, stream>>>(Wgate, wg16, 524288);
  cvt_kernel<<<2048,  256, 0, stream>>>(Wup,   wu16, 524288);
  cvt_kernel<<<2048,  256, 0, stream>>>(Wdown, wd16, 524288);

  // CSR build
  csr_count_kernel<<<32, 256, 0, stream>>>(dstIdx, cnt);
  csr_scan_kernel<<<1, 1024, 0, stream>>>(cnt, startb);
  csr_scatter_kernel<<<32, 256, 0, stream>>>(dstIdx, startb, cursor, elist);

  // x = rmsnorm(hidden, ln1) -> bf16
  rmsnorm_bf16_kernel<<<kN * kQL, 256, 0, stream>>>(hidden, ln1, x16);

  // projections (MFMA bf16)
  gemm_bf16_bt<true ><<<dim3(8, 64),  256, 0, stream>>>(x16,  wq16, nullptr, qb16,  8192, 1024, 1024);
  gemm_bf16_bt<true ><<<dim3(4, 64),  256, 0, stream>>>(x16,  wk16, nullptr, kb16,  8192,  512, 1024);
  gemm_bf16_bt<true ><<<dim3(4, 64),  256, 0, stream>>>(x16,  wv16, nullptr, vb16,  8192,  512, 1024);
  gemm_bf16_bt<true ><<<dim3(4, 512), 256, 0, stream>>>(eh16, wk16, nullptr, ekb16, 65536, 512, 1024);
  gemm_bf16_bt<true ><<<dim3(4, 512), 256, 0, stream>>>(eh16, wv16, nullptr, evb16, 65536, 512, 1024);

  // pre-RoPE Q and K in place
  rope_q_kernel<<<2048, 256, 0, stream>>>(qb16, ct, st);
  rope_k_kernel<<<1024, 256, 0, stream>>>(kb16,  0,  8192, ct, st);
  rope_k_kernel<<<8192, 256, 0, stream>>>(ekb16, 1, 65536, ct, st);

  // fused MFMA graph attention
  attn_mfma_kernel<<<2048, 256, 0, stream>>>(qb16, kb16, vb16, ekb16, evb16,
                                             srcIdx, elist, startb, agg16);

  // h = hidden + agg @ Wo^T
  gemm_bf16_bt<false><<<dim3(8, 64), 256, 0, stream>>>(agg16, wo16, hidden, hbuf, 8192, 1024, 1024);

  // MLP
  rmsnorm_bf16_kernel<<<kN * kQL, 256, 0, stream>>>(hbuf, ln2, h216);
  gemm_bf16_bt<false><<<dim3(32, 64), 256, 0, stream>>>(h216, wg16, nullptr, g, 8192, 4096, 1024);
  gemm_bf16_bt<false><<<dim3(32, 64), 256, 0, stream>>>(h216, wu16, nullptr, u, 8192, 4096, 1024);
  silu_mul_kernel<<<32768, 256, 0, stream>>>(g, u, gm16, 8388608);
  gemm_bf16_bt<false><<<dim3(8, 64), 256, 0, stream>>>(gm16, wd16, hbuf, outp, 8192, 1024, 4096);
}